// Round 6
// baseline (4222.900 us; speedup 1.0000x reference)
//
#include <hip/hip_runtime.h>

typedef unsigned int u32;
typedef unsigned long long u64;
typedef unsigned short u16;
typedef short bfrag __attribute__((ext_vector_type(8)));   // 8 x bf16 (4 VGPR)
typedef float f4 __attribute__((ext_vector_type(4)));
typedef u32 u32x4 __attribute__((ext_vector_type(4)));

#define HID 512
#define SEQT 1024
#define NIN 10
#define NC 9
#define NCL 16          // clusters (bid>>4)
#define MB  16          // batch rows per cluster
#define KSN 17          // 16 x (K=32 over H) + 1 x (x|1|pad) built locally
#define HROW 512        // exchange row: 512 bf16 = 1024B (h only; x is local now)
#define LROW 516        // LDS panel row stride u16: 1032B -> 16 rows hit 16 distinct bank pairs

#define WPACK_U16 (16*4*2*KSN*64*8)
#define WPACK_BYTES (WPACK_U16*2)
#define HEX_U16 (NCL*2*MB*HROW)
#define HEX_BYTES (HEX_U16*2)
#define FLAGS_U32 (NCL*64)         // 64 per-wave flags per cluster (4B stride)
#define FLAGS_BYTES (FLAGS_U32*4)

__device__ __forceinline__ u16 f2b(float f){
  u32 u = __float_as_uint(f);
  return (u16)((u + 0x7fffu + ((u>>16)&1u)) >> 16);   // RNE
}
__device__ __forceinline__ float b2f(u16 b){ return __uint_as_float(((u32)b)<<16); }
__device__ __forceinline__ float sigm(float x){ return 1.f/(1.f+__expf(-x)); }
__device__ __forceinline__ float tanh_(float x){ float e=__expf(2.f*x); return 1.f - 2.f/(e+1.f); }

// ---- system-scope (sc0 sc1) ops — the ONLY scope proven cross-XCD coherent
// for plain ld/st on gfx950 (r3 pass; sc0=SE r4 fail; sc1=dev r5 fail).
// LESSON (r2): inline-asm vmem is untracked by SIInsertWaitcnts — every
// ordering point needs an EXPLICIT s_waitcnt, and MFMA can be hoisted past an
// asm waitcnt (guide rule 18) — sched_barrier(0) after each drain-before-use.
__device__ __forceinline__ void st32_sys(u64 base, u32 off, u32 v){
  asm volatile("global_store_dword %0, %1, %2 sc0 sc1" :: "v"(off), "v"(v), "s"(base) : "memory");
}
__device__ __forceinline__ void st128_sys(u64 base, u32 off, u32x4 v){
  asm volatile("global_store_dwordx4 %0, %1, %2 sc0 sc1" :: "v"(off), "v"(v), "s"(base) : "memory");
}
__device__ __forceinline__ void drain_vm(){
  asm volatile("s_waitcnt vmcnt(0)" ::: "memory");
}
// dual-outstanding pipelined poll: average detect latency ~RT/2
__device__ __forceinline__ void spin_flags(u64 flgb, u32 foff, u32 tgt){
  u32 v0, v1 = 0;
  asm volatile("global_load_dword %0, %1, %2 sc0 sc1" : "=&v"(v0) : "v"(foff), "s"(flgb) : "memory");
  int guard = 0;
  for(;;){
    asm volatile("global_load_dword %0, %1, %2 sc0 sc1\n\ts_waitcnt vmcnt(1)"
                 : "=&v"(v1) : "v"(foff), "s"(flgb) : "memory");
    if (__all((int)(v0 >= tgt))) break;                 // v0 is the older load
    asm volatile("global_load_dword %0, %1, %2 sc0 sc1\n\ts_waitcnt vmcnt(1)"
                 : "=&v"(v0) : "v"(foff), "s"(flgb) : "memory");
    if (__all((int)(v1 >= tgt))) break;
    if ((guard += 2) > 400000) break;                   // fail loudly, never hang
  }
  drain_vm();                                           // retire dangling poll
  asm volatile("" :: "v"(v0), "v"(v1));
}

// ---------------- pack W_hh/W_ih/bias into MFMA B-fragment order ----------------
// (unchanged from round 3 — proven)
__global__ void pack_kernel(const float* __restrict__ W_ih, const float* __restrict__ W_hh,
                            const float* __restrict__ b_ih, const float* __restrict__ b_hh,
                            u16* __restrict__ Wpack)
{
  int tid = blockIdx.x*256 + threadIdx.x;
  if (tid >= 16*4*2*KSN*64) return;
  int lane = tid & 63;
  int rest = tid >> 6;
  int ks = rest % KSN; rest /= KSN;
  int p = rest & 1; rest >>= 1;
  int w = rest & 3; rest >>= 2;
  int g = rest;                       // 0..15
  int c2 = lane & 15;
  int kb = lane >> 4;
  int j = g*32 + w*8 + (c2 & 7);
  int gate = (p ? 2 : 0) + (c2 >= 8 ? 1 : 0);   // i,f,g,o = 0,1,2,3
  int R = gate*HID + j;

  union { u16 s[8]; bfrag v; } o;
  if (ks < 16) {
    const float* src = W_hh + (size_t)R*HID + ks*32 + kb*8;
    #pragma unroll
    for (int e=0;e<8;e++) o.s[e] = f2b(src[e]);
  } else {
    #pragma unroll
    for (int e=0;e<8;e++) {
      int k = kb*8 + e;
      float v = (k < NIN) ? W_ih[(size_t)R*NIN + k] : (k==NIN ? (b_ih[R]+b_hh[R]) : 0.f);
      o.s[e] = f2b(v);
    }
  }
  *(bfrag*)(Wpack + (size_t)tid*8) = o.v;
}

// ---------------- init exchange buffers (h=0) + flags ----------------
__global__ void init_kernel(u16* __restrict__ hex_, u32* __restrict__ flags)
{
  int tid = blockIdx.x*256 + threadIdx.x;
  if (tid < HEX_U16) hex_[tid] = 0;
  if (tid < FLAGS_U32) flags[tid] = 0;
}

// ---------------- persistent LSTM kernel ----------------
// grid = 256 blocks (1/CU), 256 threads (4 waves). cluster = bid>>4, rank g.
// System-scope exchange; per-wave flags; wave0-only poll; logits in the
// staging-load shadow (lag-2 rowbuf).
__global__ __launch_bounds__(256, 1) void lstm_kernel(
    const float* __restrict__ inputs, const float* __restrict__ lin_W,
    const float* __restrict__ lin_b, const u16* __restrict__ Wpack,
    u16* __restrict__ hex_, u32* __restrict__ flags, float* __restrict__ out)
{
  const int bid = blockIdx.x;
  const int cl = bid >> 4;
  const int g = bid & 15;
  const int tid = threadIdx.x;
  const int w = tid >> 6;
  const int lane = tid & 63;
  const int c2 = lane & 15;
  const int kb = lane >> 4;
  const int jb = g*32 + w*8;
  const bool lowhalf = (c2 < 8);
  const int vb = cl*MB + g;              // batch row / output row

  __shared__ __align__(16) u16 panel[MB*LROW];
  __shared__ __align__(16) u16 rowbuf[2][HID];

  // persistent B-fragments: 2 ntiles x 17 ksteps
  bfrag wf0[KSN], wf1[KSN];
  {
    const u16* base = Wpack + ((size_t)(g*4+w)*2)*KSN*64*8;
    #pragma unroll
    for (int ks=0;ks<KSN;ks++) wf0[ks] = *(const bfrag*)(base + ((size_t)ks*64 + lane)*8);
    #pragma unroll
    for (int ks=0;ks<KSN;ks++) wf1[ks] = *(const bfrag*)(base + ((size_t)(KSN+ks)*64 + lane)*8);
  }
  float lw[3][8]; float lb[3];
  if (w < 3) {
    #pragma unroll
    for (int cc=0;cc<3;cc++){
      int cls = w*3+cc;
      lb[cc] = lin_b[cls];
      #pragma unroll
      for (int e=0;e<8;e++) lw[cc][e] = lin_W[(size_t)cls*HID + lane*8 + e];
    }
  }

  float cst[4] = {0.f,0.f,0.f,0.f};

  const u64 ex0 = (u64)(hex_ + (size_t)(cl*2+0)*MB*HROW);
  const u64 ex1 = (u64)(hex_ + (size_t)(cl*2+1)*MB*HROW);
  const u64 flgb = (u64)(flags + (size_t)cl*64);
  const u32 foff = (u32)(lane*4);

  // staging: 1024 x 16B chunks, 4/thread; row = chunk>>6, rem = chunk&63
  u32 go[4], lo[4];
  #pragma unroll
  for (int i=0;i<4;i++){
    u32 chunk = (u32)tid + (u32)i*256u;
    go[i] = (chunk>>6)*1024u + (chunk&63u)*16u;
    lo[i] = (chunk>>6)*(LROW*2u) + (chunk&63u)*16u;
  }

  const float* xrow = inputs + (size_t)(cl*MB + c2)*SEQT*NIN;   // row c2 inputs

  for (int t = 0; t < SEQT; ++t) {
    const u64 cur = (t & 1) ? ex1 : ex0;
    const u64 nxt = (t & 1) ? ex0 : ex1;

    // ---- build local x|1 fragment for step t (cached loads, overlaps poll)
    union { u32 u[4]; bfrag v; } xu;
    xu.u[0]=0; xu.u[1]=0; xu.u[2]=0; xu.u[3]=0;
    {
      const float* p = xrow + (size_t)t*NIN;
      if (kb == 0) {
        #pragma unroll
        for (int q=0;q<4;q++) xu.u[q] = (u32)f2b(p[2*q]) | ((u32)f2b(p[2*q+1])<<16);
      } else if (kb == 1) {
        xu.u[0] = (u32)f2b(p[8]) | ((u32)f2b(p[9])<<16);
        xu.u[1] = 0x3F80u;                 // k=10 -> 1.0 (bias column)
      }
    }

    // ---- wave0 polls all 64 per-wave flags; others sleep at S0
    if (w == 0) spin_flags(flgb, foff, (u32)t);
    __syncthreads();                       // S0

    // ---- issue panel staging loads (16KB block-wide), no wait yet
    u32x4 r0,r1,r2,r3;
    asm volatile(
      "global_load_dwordx4 %0, %4, %8 sc0 sc1\n\t"
      "global_load_dwordx4 %1, %5, %8 sc0 sc1\n\t"
      "global_load_dwordx4 %2, %6, %8 sc0 sc1\n\t"
      "global_load_dwordx4 %3, %7, %8 sc0 sc1"
      : "=&v"(r0), "=&v"(r1), "=&v"(r2), "=&v"(r3)
      : "v"(go[0]), "v"(go[1]), "v"(go[2]), "v"(go[3]), "s"(cur)
      : "memory");

    // ---- logits[t-2] from rowbuf[(t-1)&1] = h_{t-1}, in the load shadow
    if (w < 3 && t >= 2) {
      bfrag hx = *(const bfrag*)&rowbuf[(t-1)&1][lane*8];
      float hv[8];
      #pragma unroll
      for (int e=0;e<8;e++) hv[e] = b2f((u16)hx[e]);
      #pragma unroll
      for (int cc=0;cc<3;cc++){
        float s = 0.f;
        #pragma unroll
        for (int e=0;e<8;e++) s += hv[e]*lw[cc][e];
        #pragma unroll
        for (int off=1;off<64;off<<=1) s += __shfl_xor(s, off, 64);
        if (lane == 0)
          out[((size_t)vb*SEQT + (t-2))*NC + (w*3+cc)] = s + lb[cc];
      }
    }

    drain_vm();                            // staging (+ logit stores) complete
    __builtin_amdgcn_sched_barrier(0);
    *(u32x4*)((char*)panel + lo[0]) = r0;
    *(u32x4*)((char*)panel + lo[1]) = r1;
    *(u32x4*)((char*)panel + lo[2]) = r2;
    *(u32x4*)((char*)panel + lo[3]) = r3;
    __syncthreads();                       // S1: panel ready

    // wave3 snapshots row g (h_t) for the lag-2 logits
    if (w == 3)
      *(bfrag*)&rowbuf[t&1][lane*8] = *(const bfrag*)&panel[g*LROW + lane*8];

    // ---- gates = [h | x,1] @ Wpack^T   (f32 accum)
    f4 acc0 = {0.f,0.f,0.f,0.f}, acc1 = {0.f,0.f,0.f,0.f};
    #pragma unroll
    for (int ks=0;ks<16;ks++){
      bfrag av = *(const bfrag*)&panel[c2*LROW + ks*32 + kb*8];
      acc0 = __builtin_amdgcn_mfma_f32_16x16x32_bf16(av, wf0[ks], acc0, 0,0,0);
      acc1 = __builtin_amdgcn_mfma_f32_16x16x32_bf16(av, wf1[ks], acc1, 0,0,0);
    }
    acc0 = __builtin_amdgcn_mfma_f32_16x16x32_bf16(xu.v, wf0[16], acc0, 0,0,0);
    acc1 = __builtin_amdgcn_mfma_f32_16x16x32_bf16(xu.v, wf1[16], acc1, 0,0,0);

    // ---- activations. lanes c2<8: acc0=i, acc1=g ; c2>=8: acc0=f, acc1=o.
    u16 hb[4];
    #pragma unroll
    for (int r=0;r<4;r++){
      float a0 = sigm(acc0[r]);
      float a1 = lowhalf ? tanh_(acc1[r]) : sigm(acc1[r]);
      float p0 = __shfl_xor(a0, 8, 64);
      float p1 = __shfl_xor(a1, 8, 64);
      float ii = lowhalf ? a0 : p0;
      float ff = lowhalf ? p0 : a0;
      float gg = lowhalf ? a1 : p1;
      float oo = lowhalf ? p1 : a1;
      float cn = ff*cst[r] + ii*gg;
      cst[r] = cn;
      hb[r] = f2b(oo * tanh_(cn));
    }

    // ---- publish h slice: gather 8 cols into lane c2==0, one dwordx4/row
    #pragma unroll
    for (int r=0;r<4;r++){
      u32 pv = (u32)hb[r] | (((u32)(u16)__shfl_down((int)hb[r], 1, 64)) << 16);
      u32 p1 = __shfl_down(pv, 2, 64);
      u32 p2 = __shfl_down(pv, 4, 64);
      u32 p3 = __shfl_down(pv, 6, 64);
      if (c2 == 0) {
        u32x4 pk = {pv, p1, p2, p3};
        st128_sys(nxt, (u32)((kb*4+r)*1024 + jb*2), pk);
      }
    }

    // ---- per-wave release: own stores drained -> own flag
    drain_vm();
    if (lane == 0)
      st32_sys(flgb, (u32)((g*4+w)*4), (u32)(t+1));
  }

  // ---- epilogue: out[T-2] from rowbuf[1] (h_{T-1}); out[T-1] from h_T (ex0)
  if (w == 0) spin_flags(flgb, foff, (u32)SEQT);
  __syncthreads();
  if (w < 3) {
    {
      bfrag hx = *(const bfrag*)&rowbuf[(SEQT-1)&1][lane*8];
      float hv[8];
      #pragma unroll
      for (int e=0;e<8;e++) hv[e] = b2f((u16)hx[e]);
      #pragma unroll
      for (int cc=0;cc<3;cc++){
        float s = 0.f;
        #pragma unroll
        for (int e=0;e<8;e++) s += hv[e]*lw[cc][e];
        #pragma unroll
        for (int off=1;off<64;off<<=1) s += __shfl_xor(s, off, 64);
        if (lane == 0)
          out[((size_t)vb*SEQT + (SEQT-2))*NC + (w*3+cc)] = s + lb[cc];
      }
    }
    {
      u32x4 rr;
      asm volatile("global_load_dwordx4 %0, %1, %2 sc0 sc1\n\ts_waitcnt vmcnt(0)"
                   : "=&v"(rr) : "v"((u32)(g*1024 + lane*16)), "s"(ex0) : "memory");
      float hv[8];
      #pragma unroll
      for (int e=0;e<4;e++){
        hv[2*e]   = b2f((u16)(rr[e] & 0xffffu));
        hv[2*e+1] = b2f((u16)(rr[e] >> 16));
      }
      #pragma unroll
      for (int cc=0;cc<3;cc++){
        float s = 0.f;
        #pragma unroll
        for (int e=0;e<8;e++) s += hv[e]*lw[cc][e];
        #pragma unroll
        for (int off=1;off<64;off<<=1) s += __shfl_xor(s, off, 64);
        if (lane == 0)
          out[((size_t)vb*SEQT + (SEQT-1))*NC + (w*3+cc)] = s + lb[cc];
      }
    }
  }
}

extern "C" void kernel_launch(void* const* d_in, const int* in_sizes, int n_in,
                              void* d_out, int out_size, void* d_ws, size_t ws_size,
                              hipStream_t stream)
{
  const float* inputs = (const float*)d_in[0];
  const float* W_ih   = (const float*)d_in[1];
  const float* W_hh   = (const float*)d_in[2];
  const float* b_ih   = (const float*)d_in[3];
  const float* b_hh   = (const float*)d_in[4];
  const float* lin_W  = (const float*)d_in[5];
  const float* lin_b  = (const float*)d_in[6];

  u16* Wpack = (u16*)d_ws;
  u16* hex_  = (u16*)((char*)d_ws + WPACK_BYTES);
  u32* flags = (u32*)((char*)d_ws + WPACK_BYTES + HEX_BYTES);

  pack_kernel<<<(16*4*2*KSN*64 + 255)/256, 256, 0, stream>>>(W_ih, W_hh, b_ih, b_hh, Wpack);
  init_kernel<<<(HEX_U16 + 255)/256, 256, 0, stream>>>(hex_, flags);
  lstm_kernel<<<256, 256, 0, stream>>>(inputs, lin_W, lin_b, Wpack, hex_, flags, (float*)d_out);
}